// Round 1
// baseline (303.748 us; speedup 1.0000x reference)
//
#include <hip/hip_runtime.h>
#include <math.h>

// Single-dispatch fused pipeline (round 9):
//   x (64,8,2048) -> conv1(16,1,3,5 pad(1,2)) +bias,relu -> maxpool W/2 -> h1 fp16 (LDS)
//   -> conv2 via fp16 MFMA 32x32x16 (A-fragments gathered from w2 in-kernel, 1-tap prefetch)
//   -> +bias, relu(maxpool), 16-lane DPP reduce -> fp32 atomicAdd into gacc[64][32]
//   -> per-b completion counter; last-finishing block of each b runs the tail
//      (mean -> relu(g@w_glob) -> LN -> v -> attn_out -> mlp) on wave 0, shuffle-only.
// prep_frags and tail_kernel launches eliminated; 1 MB partials buffer eliminated.
// Workspace: gacc 8192 B @0, cnt 256 B @8192, zeroed by one hipMemsetAsync node.

typedef __attribute__((ext_vector_type(4))) _Float16 f16x4;
typedef __attribute__((ext_vector_type(8)))  _Float16 f16x8;
typedef __attribute__((ext_vector_type(16))) float    f32x16;

#define WT 64
#define NT 16
#define H1_OFF   0          // 10 rows * 68 cols * 16 ic * 2B = 21760
#define XS_OFF   21760      // 8*144*4 = 4608
#define LDS_BYTES 26368

template <int CTRL>
__device__ __forceinline__ float dppf(float v) {
    return __uint_as_float(__builtin_amdgcn_update_dpp(
        0u, __float_as_uint(v), CTRL, 0xF, 0xF, true));
}
#define DPP_XOR1 0xB1       // quad_perm [1,0,3,2]
#define DPP_XOR2 0x4E       // quad_perm [2,3,0,1]
#define DPP_ROR4 0x124      // row_ror:4
#define DPP_ROR8 0x128      // row_ror:8

__global__ __launch_bounds__(256, 4) void conv_fused(
    const float* __restrict__ x,
    const float* __restrict__ w1, const float* __restrict__ b1,
    const float* __restrict__ w2, const float* __restrict__ b2,
    const float* __restrict__ w_glob, const float* __restrict__ b_glob,
    const float* __restrict__ g_glob, const float* __restrict__ be_glob,
    const float* __restrict__ in_proj_w, const float* __restrict__ in_proj_b,
    const float* __restrict__ out_w, const float* __restrict__ out_b,
    const float* __restrict__ mlp_w1, const float* __restrict__ mlp_b1,
    const float* __restrict__ mlp_w2, const float* __restrict__ mlp_b2,
    float* __restrict__ gacc,    // [64][32], zero-init per launch
    int*   __restrict__ cnt,     // [64], zero-init per launch
    float* __restrict__ out)     // [64][10]
{
    const int wt  = blockIdx.x;      // 0..15
    const int b   = blockIdx.y;      // 0..63
    const int tid = threadIdx.x;     // 0..255
    const int w0  = wt * WT;

    __shared__ __align__(16) unsigned int ldsu[LDS_BYTES / 4];
    __shared__ int lastf;
    _Float16* h1 = (_Float16*)((char*)ldsu + H1_OFF);  // [(rr*68+c)*16+ic], rr=0..9 (0,9 zero)
    float*    xs = (float*)((char*)ldsu + XS_OFF);     // [8][144]

    // ---- per-thread conv1 weights: ic quad q = tid&3 (thread-constant) ----
    const int q = tid & 3;
    float wreg[60];
    float bias1[4];
    #pragma unroll
    for (int j = 0; j < 4; ++j) {
        #pragma unroll
        for (int k = 0; k < 15; ++k) wreg[j * 15 + k] = w1[(q * 4 + j) * 15 + k];
        bias1[j] = b1[q * 4 + j];
    }

    // ---- phase 0: stage x tile (cols t0..t0+139), zero pad rows rr=0,9 ----
    const int t0 = 2 * w0 - 6;
    for (int i = tid; i < 8 * 144; i += 256) {
        int r = i / 144, tl = i - r * 144;
        int t = t0 + tl;
        float v = 0.f;
        if (tl < 140 && t >= 0 && t < 2048) v = x[(b * 8 + r) * 2048 + t];
        xs[i] = v;
    }
    {
        unsigned int* hh = (unsigned int*)h1;
        for (int i = tid; i < 544; i += 256) {       // each padded row = 544 dwords
            hh[i] = 0u; hh[4896 + i] = 0u;
        }
    }
    __syncthreads();

    // ---- phase 1: conv1 + bias + relu + maxpool -> h1 (fp16) ----
    #pragma unroll
    for (int pass = 0; pass < 3; ++pass) {
        if (pass == 2 && tid >= 32) break;
        const int idx = (tid >> 2) + pass * 64;      // 0..135
        const int r   = idx / 17;
        const int c4  = idx - r * 17;
        const int cb  = c4 * 8;
        float xv[3][12];
        #pragma unroll
        for (int pq = 0; pq < 3; ++pq) {
            int rr = r + pq - 1;
            if (rr >= 0 && rr < 8) {
                const float4* p = (const float4*)&xs[rr * 144 + cb];
                float4 a0 = p[0], a1 = p[1], a2 = p[2];
                xv[pq][0]=a0.x; xv[pq][1]=a0.y; xv[pq][2]=a0.z; xv[pq][3]=a0.w;
                xv[pq][4]=a1.x; xv[pq][5]=a1.y; xv[pq][6]=a1.z; xv[pq][7]=a1.w;
                xv[pq][8]=a2.x; xv[pq][9]=a2.y; xv[pq][10]=a2.z; xv[pq][11]=a2.w;
            } else {
                #pragma unroll
                for (int z = 0; z < 12; ++z) xv[pq][z] = 0.f;
            }
        }
        #pragma unroll
        for (int cc = 0; cc < 4; ++cc) {
            const int wc = w0 - 2 + 4 * c4 + cc;
            f16x4 hv;
            #pragma unroll
            for (int j = 0; j < 4; ++j) {
                float c0 = bias1[j], c1 = bias1[j];
                #pragma unroll
                for (int kh = 0; kh < 3; ++kh)
                    #pragma unroll
                    for (int kw = 0; kw < 5; ++kw) {
                        float wgt = wreg[j * 15 + kh * 5 + kw];
                        c0 = fmaf(xv[kh][2 * cc + kw],     wgt, c0);
                        c1 = fmaf(xv[kh][2 * cc + kw + 1], wgt, c1);
                    }
                float v = fmaxf(fmaxf(c0, c1), 0.f);
                if (wc < 0 || wc >= 1024) v = 0.f;
                hv[j] = (_Float16)v;
            }
            *(f16x4*)&h1[((r + 1) * 68 + 4 * c4 + cc) * 16 + q * 4] = hv;  // 8B store
        }
    }
    __syncthreads();

    // ---- phase 2: conv2 via fp16 MFMA. wave handles h rows {2w,2w+1} x wn0 {0,32} ----
    const int lane  = tid & 63;
    const int wave  = tid >> 6;
    const int laneN = lane & 31;
    const int icoff = (lane >> 5) * 8;
    const int half  = lane >> 5;

    f32x16 acc[4];
    #pragma unroll
    for (int nt = 0; nt < 4; ++nt)
        #pragma unroll
        for (int r = 0; r < 16; ++r) acc[nt][r] = 0.f;

    // A-fragment for tap 0 gathered directly from w2 (replaces prep_frags kernel).
    // Same lane->element mapping as before: oc = laneN, ic = icoff..icoff+7.
    f16x8 a_cur;
    {
        float af[8];
        #pragma unroll
        for (int j = 0; j < 8; ++j)
            af[j] = w2[((laneN * 16 + icoff + j) * 3 + 0) * 5 + 0];
        #pragma unroll
        for (int j = 0; j < 8; ++j) a_cur[j] = (_Float16)af[j];
    }

    for (int t = 0; t < 15; ++t) {
        const int kh = t / 5, kw = t - kh * 5;       // wave-uniform
        float anf[8];                                // prefetch tap t+1 (f32; cvt AFTER MFMAs)
        if (t < 14) {
            const int t1  = t + 1;
            const int kh1 = t1 / 5, kw1 = t1 - kh1 * 5;
            #pragma unroll
            for (int j = 0; j < 8; ++j)
                anf[j] = w2[((laneN * 16 + icoff + j) * 3 + kh1) * 5 + kw1];
        }
        #pragma unroll
        for (int nt = 0; nt < 4; ++nt) {
            int hrow = 2 * wave + (nt >> 1);
            int wn0  = (nt & 1) * 32;
            int idx  = ((hrow + kh) * 68 + wn0 + laneN + kw) * 16 + icoff;
            f16x8 bv = *(const f16x8*)&h1[idx];
            acc[nt] = __builtin_amdgcn_mfma_f32_32x32x16_f16(a_cur, bv, acc[nt], 0, 0, 0);
        }
        if (t < 14) {
            f16x8 an;
            #pragma unroll
            for (int j = 0; j < 8; ++j) an[j] = (_Float16)anf[j];
            a_cur = an;
        }
    }

    // ---- epilogue (VALU/DPP): +bias, relu(maxpool) via DPP xor1, 16-lane DPP sum ----
    float b2v[16], sums[16];
    #pragma unroll
    for (int r = 0; r < 16; ++r) {
        b2v[r]  = b2[(r & 3) + 8 * (r >> 2) + 4 * half];
        sums[r] = 0.f;
    }
    #pragma unroll
    for (int nt = 0; nt < 4; ++nt)
        #pragma unroll
        for (int r = 0; r < 16; ++r) {
            float d = acc[nt][r] + b2v[r];
            float o = fmaxf(fmaxf(d, dppf<DPP_XOR1>(d)), 0.f);  // pool pair + relu
            sums[r] += o;                                        // counts each pair twice
        }
    #pragma unroll
    for (int r = 0; r < 16; ++r) {
        float s = sums[r];
        s += dppf<DPP_XOR1>(s);
        s += dppf<DPP_XOR2>(s);
        s += dppf<DPP_ROR4>(s);
        s += dppf<DPP_ROR8>(s);      // full sum within each 16-lane group
        sums[r] = s;
    }
    if ((lane & 15) == 0) {          // lanes 0,16,32,48: two n-halves x two K-halves
        #pragma unroll
        for (int r = 0; r < 16; ++r) {
            int oc = (r & 3) + 8 * (r >> 2) + 4 * half;
            atomicAdd(&gacc[b * 32 + oc], 0.5f * sums[r]);
        }
    }

    // ---- per-b completion counter: last of the 16 blocks for this b runs the tail ----
    __threadfence();                 // release: gacc atomics visible device-wide
    __syncthreads();                 // all threads' fences done before the counter bump
    if (tid == 0) lastf = (atomicAdd(&cnt[b], 1) == NT - 1) ? 1 : 0;
    __syncthreads();
    if (!lastf || tid >= 64) return;
    __threadfence();                 // acquire: see all 16 blocks' gacc contributions

    // ---- tail (wave 0, shuffle-only; one wave per b, overlapped across blocks) ----
    const int e  = tid;              // 0..63
    const int eo = e & 31;
    float gval = gacc[b * 32 + eo] * (1.f / 4096.f);   // mean over 8*512

    float accv = b_glob[e];
    #pragma unroll
    for (int i = 0; i < 32; ++i) accv = fmaf(__shfl(gval, i), w_glob[i * 64 + e], accv);
    accv = fmaxf(accv, 0.f);

    float m = accv;
    #pragma unroll
    for (int k = 32; k >= 1; k >>= 1) m += __shfl_xor(m, k);
    m *= (1.f / 64.f);
    float dd = accv - m;
    float vv = dd * dd;
    #pragma unroll
    for (int k = 32; k >= 1; k >>= 1) vv += __shfl_xor(vv, k);
    vv *= (1.f / 64.f);
    float gl = dd * (1.f / sqrtf(vv + 1e-5f)) * g_glob[e] + be_glob[e];

    float vval = in_proj_b[128 + e];
    #pragma unroll 16
    for (int j = 0; j < 64; ++j) vval = fmaf(__shfl(gl, j), in_proj_w[(128 + e) * 64 + j], vval);

    float ao = out_b[e];
    #pragma unroll 16
    for (int j = 0; j < 64; ++j) ao = fmaf(__shfl(vval, j), out_w[e * 64 + j], ao);

    float hm = mlp_b1[eo];
    #pragma unroll 16
    for (int j = 0; j < 64; ++j) hm = fmaf(__shfl(ao, j), mlp_w1[j * 32 + eo], hm);
    hm = fmaxf(hm, 0.f);

    const int ee = (e < 10) ? e : 0;                 // keep shuffle sources active
    float o = mlp_b2[ee];
    #pragma unroll
    for (int i = 0; i < 32; ++i) o = fmaf(__shfl(hm, i), mlp_w2[i * 10 + ee], o);
    if (e < 10) out[b * 10 + e] = o;
}

extern "C" void kernel_launch(void* const* d_in, const int* in_sizes, int n_in,
                              void* d_out, int out_size, void* d_ws, size_t ws_size,
                              hipStream_t stream) {
    const float* x        = (const float*)d_in[0];
    const float* conv1_w  = (const float*)d_in[6];
    const float* conv1_b  = (const float*)d_in[7];
    const float* conv2_w  = (const float*)d_in[8];
    const float* conv2_b  = (const float*)d_in[9];
    const float* w_glob   = (const float*)d_in[10];
    const float* b_glob   = (const float*)d_in[11];
    const float* g_glob   = (const float*)d_in[12];
    const float* be_glob  = (const float*)d_in[13];
    const float* in_proj_w = (const float*)d_in[14];
    const float* in_proj_b = (const float*)d_in[15];
    const float* out_w    = (const float*)d_in[16];
    const float* out_b    = (const float*)d_in[17];
    const float* mlp_w1   = (const float*)d_in[18];
    const float* mlp_b1   = (const float*)d_in[19];
    const float* mlp_w2   = (const float*)d_in[20];
    const float* mlp_b2   = (const float*)d_in[21];

    float* gacc = (float*)d_ws;                       // 64*32*4 = 8192 B
    int*   cnt  = (int*)((char*)d_ws + 8192);         // 64*4 = 256 B

    hipMemsetAsync(d_ws, 0, 8192 + 256, stream);      // graph-capturable memset node

    dim3 grid(NT, 64);
    conv_fused<<<grid, 256, 0, stream>>>(x, conv1_w, conv1_b, conv2_w, conv2_b,
                                         w_glob, b_glob, g_glob, be_glob,
                                         in_proj_w, in_proj_b, out_w, out_b,
                                         mlp_w1, mlp_b1, mlp_w2, mlp_b2,
                                         gacc, cnt, (float*)d_out);
}

// Round 2
// 190.099 us; speedup vs baseline: 1.5978x; 1.5978x over previous
//
#include <hip/hip_runtime.h>
#include <math.h>

// Round 10: revert to verified round-0 3-dispatch structure (125 us), keep only the
// fence-free improvement: conv2 epilogue atomicAdds into gacc[64][32] (8 KB) instead of
// writing part[] (1 MB); tail_kernel reads gacc directly (atomic visibility across the
// kernel boundary needs no fences). Round-1 lesson: in-loop scattered w2 gather was
// TA-bound (~64 lines/load instr) and __threadfence L2 writebacks serialized the chip.
//
// conv2: single-product fp16 MFMA 32x32x16 (validated: absmax 1.2e-4 << 7.5e-4).

typedef __attribute__((ext_vector_type(4))) _Float16 f16x4;
typedef __attribute__((ext_vector_type(8)))  _Float16 f16x8;
typedef __attribute__((ext_vector_type(16))) float    f32x16;

#define WT 64
#define NT 16
#define H1_OFF   0          // 10 rows * 68 cols * 16 ic * 2B = 21760
#define XS_OFF   21760      // 8*144*4 = 4608
#define LDS_BYTES 26368

template <int CTRL>
__device__ __forceinline__ float dppf(float v) {
    return __uint_as_float(__builtin_amdgcn_update_dpp(
        0u, __float_as_uint(v), CTRL, 0xF, 0xF, true));
}
#define DPP_XOR1 0xB1       // quad_perm [1,0,3,2]
#define DPP_XOR2 0x4E       // quad_perm [2,3,0,1]
#define DPP_ROR4 0x124      // row_ror:4
#define DPP_ROR8 0x128      // row_ror:8

// Build conv2-weight fp16 MFMA A-fragments once: fragg[15][64][8] (coalesced consumer loads)
__global__ void prep_frags(const float* __restrict__ w2, _Float16* __restrict__ fragg) {
    const int t    = blockIdx.x;       // 0..14 (tap)
    const int lane = threadIdx.x;      // 0..63
    const int kh   = t / 5, kw = t - kh * 5;
    const int oc   = lane & 31;
    const int ic0  = (lane >> 5) * 8;
    f16x8 hv;
    #pragma unroll
    for (int j = 0; j < 8; ++j)
        hv[j] = (_Float16)w2[((oc * 16 + ic0 + j) * 3 + kh) * 5 + kw];
    *(f16x8*)&fragg[(t * 64 + lane) * 8] = hv;
}

__global__ __launch_bounds__(256, 4) void conv_fused(
    const float* __restrict__ x,
    const float* __restrict__ w1, const float* __restrict__ b1,
    const float* __restrict__ b2,
    const _Float16* __restrict__ fragg,
    float* __restrict__ gacc)    // [64 b][32 oc], zeroed per launch; fp32 atomic accum
{
    const int wt  = blockIdx.x;      // 0..15
    const int b   = blockIdx.y;      // 0..63
    const int tid = threadIdx.x;     // 0..255
    const int w0  = wt * WT;

    __shared__ __align__(16) unsigned int ldsu[LDS_BYTES / 4];
    _Float16* h1 = (_Float16*)((char*)ldsu + H1_OFF);  // [(rr*68+c)*16+ic], rr=0..9 (0,9 zero)
    float*    xs = (float*)((char*)ldsu + XS_OFF);     // [8][144]

    // ---- per-thread conv1 weights: ic quad q = tid&3 (thread-constant) ----
    const int q = tid & 3;
    float wreg[60];
    float bias1[4];
    #pragma unroll
    for (int j = 0; j < 4; ++j) {
        #pragma unroll
        for (int k = 0; k < 15; ++k) wreg[j * 15 + k] = w1[(q * 4 + j) * 15 + k];
        bias1[j] = b1[q * 4 + j];
    }

    // ---- phase 0: stage x tile (cols t0..t0+139), zero pad rows rr=0,9 ----
    const int t0 = 2 * w0 - 6;
    for (int i = tid; i < 8 * 144; i += 256) {
        int r = i / 144, tl = i - r * 144;
        int t = t0 + tl;
        float v = 0.f;
        if (tl < 140 && t >= 0 && t < 2048) v = x[(b * 8 + r) * 2048 + t];
        xs[i] = v;
    }
    {
        unsigned int* hh = (unsigned int*)h1;
        for (int i = tid; i < 544; i += 256) {       // each padded row = 544 dwords
            hh[i] = 0u; hh[4896 + i] = 0u;
        }
    }
    __syncthreads();

    // ---- phase 1: conv1 + bias + relu + maxpool -> h1 (fp16) ----
    // item id e in [0,544): idx = e>>2 in [0,136) -> (r = idx/17, c4 = idx%17); quad q = e&3.
    #pragma unroll
    for (int pass = 0; pass < 3; ++pass) {
        if (pass == 2 && tid >= 32) break;
        const int idx = (tid >> 2) + pass * 64;      // 0..135
        const int r   = idx / 17;
        const int c4  = idx - r * 17;
        const int cb  = c4 * 8;
        float xv[3][12];
        #pragma unroll
        for (int pq = 0; pq < 3; ++pq) {
            int rr = r + pq - 1;
            if (rr >= 0 && rr < 8) {
                const float4* p = (const float4*)&xs[rr * 144 + cb];
                float4 a0 = p[0], a1 = p[1], a2 = p[2];
                xv[pq][0]=a0.x; xv[pq][1]=a0.y; xv[pq][2]=a0.z; xv[pq][3]=a0.w;
                xv[pq][4]=a1.x; xv[pq][5]=a1.y; xv[pq][6]=a1.z; xv[pq][7]=a1.w;
                xv[pq][8]=a2.x; xv[pq][9]=a2.y; xv[pq][10]=a2.z; xv[pq][11]=a2.w;
            } else {
                #pragma unroll
                for (int z = 0; z < 12; ++z) xv[pq][z] = 0.f;
            }
        }
        #pragma unroll
        for (int cc = 0; cc < 4; ++cc) {
            const int wc = w0 - 2 + 4 * c4 + cc;
            f16x4 hv;
            #pragma unroll
            for (int j = 0; j < 4; ++j) {
                float c0 = bias1[j], c1 = bias1[j];
                #pragma unroll
                for (int kh = 0; kh < 3; ++kh)
                    #pragma unroll
                    for (int kw = 0; kw < 5; ++kw) {
                        float wgt = wreg[j * 15 + kh * 5 + kw];
                        c0 = fmaf(xv[kh][2 * cc + kw],     wgt, c0);
                        c1 = fmaf(xv[kh][2 * cc + kw + 1], wgt, c1);
                    }
                float v = fmaxf(fmaxf(c0, c1), 0.f);
                if (wc < 0 || wc >= 1024) v = 0.f;
                hv[j] = (_Float16)v;
            }
            *(f16x4*)&h1[((r + 1) * 68 + 4 * c4 + cc) * 16 + q * 4] = hv;  // 8B store
        }
    }
    __syncthreads();

    // ---- phase 2: conv2 via fp16 MFMA. wave handles h rows {2w,2w+1} x wn0 {0,32} ----
    const int lane  = tid & 63;
    const int wave  = tid >> 6;
    const int laneN = lane & 31;
    const int icoff = (lane >> 5) * 8;
    const int half  = lane >> 5;

    f32x16 acc[4];
    #pragma unroll
    for (int nt = 0; nt < 4; ++nt)
        #pragma unroll
        for (int r = 0; r < 16; ++r) acc[nt][r] = 0.f;

    const f16x8* Ag = (const f16x8*)fragg;
    f16x8 a_cur = Ag[lane];                          // tap 0 (L1/L2-resident, coalesced)
    for (int t = 0; t < 15; ++t) {
        f16x8 a_nxt = (t < 14) ? Ag[(t + 1) * 64 + lane] : a_cur;  // 1-deep prefetch
        int kh = t / 5, kw = t - kh * 5;             // wave-uniform
        #pragma unroll
        for (int nt = 0; nt < 4; ++nt) {
            int hrow = 2 * wave + (nt >> 1);
            int wn0  = (nt & 1) * 32;
            int idx  = ((hrow + kh) * 68 + wn0 + laneN + kw) * 16 + icoff;
            f16x8 bv = *(const f16x8*)&h1[idx];
            acc[nt] = __builtin_amdgcn_mfma_f32_32x32x16_f16(a_cur, bv, acc[nt], 0, 0, 0);
        }
        a_cur = a_nxt;
    }

    // ---- epilogue (VALU/DPP): +bias, relu(maxpool) via DPP xor1, 16-lane DPP sum ----
    float b2v[16], sums[16];
    #pragma unroll
    for (int r = 0; r < 16; ++r) {
        b2v[r]  = b2[(r & 3) + 8 * (r >> 2) + 4 * half];
        sums[r] = 0.f;
    }
    #pragma unroll
    for (int nt = 0; nt < 4; ++nt)
        #pragma unroll
        for (int r = 0; r < 16; ++r) {
            float d = acc[nt][r] + b2v[r];
            float o = fmaxf(fmaxf(d, dppf<DPP_XOR1>(d)), 0.f);  // pool pair + relu
            sums[r] += o;                                        // counts each pair twice
        }
    #pragma unroll
    for (int r = 0; r < 16; ++r) {
        float s = sums[r];
        s += dppf<DPP_XOR1>(s);
        s += dppf<DPP_XOR2>(s);
        s += dppf<DPP_ROR4>(s);
        s += dppf<DPP_ROR8>(s);      // full sum within each 16-lane group
        sums[r] = s;
    }
    if ((lane & 15) == 0) {          // lanes 0,16,32,48: two n-halves x two K-halves
        #pragma unroll
        for (int r = 0; r < 16; ++r) {
            int oc = (r & 3) + 8 * (r >> 2) + 4 * half;
            atomicAdd(&gacc[b * 32 + oc], 0.5f * sums[r]);   // device-scope, no fences
        }
    }
}

__global__ void tail_kernel(
    const float* __restrict__ gacc,
    const float* __restrict__ w_glob, const float* __restrict__ b_glob,
    const float* __restrict__ g_glob, const float* __restrict__ be_glob,
    const float* __restrict__ in_proj_w, const float* __restrict__ in_proj_b,
    const float* __restrict__ out_w, const float* __restrict__ out_b,
    const float* __restrict__ mlp_w1, const float* __restrict__ mlp_b1,
    const float* __restrict__ mlp_w2, const float* __restrict__ mlp_b2,
    float* __restrict__ out)
{
    const int b = blockIdx.x;        // 0..63
    const int e = threadIdx.x;       // 0..63 (one wave)
    __shared__ float gs[32], glob_s[64], vs[64], aos[64], hms[32];

    if (e < 32) gs[e] = gacc[b * 32 + e] * (1.f / 4096.f);  // mean over 8*512
    __syncthreads();

    float acc = b_glob[e];
    #pragma unroll
    for (int i = 0; i < 32; ++i) acc = fmaf(gs[i], w_glob[i * 64 + e], acc);
    acc = fmaxf(acc, 0.f);

    float m = acc;
    #pragma unroll
    for (int k = 32; k >= 1; k >>= 1) m += __shfl_xor(m, k);
    m *= (1.f / 64.f);
    float d = acc - m;
    float vv = d * d;
    #pragma unroll
    for (int k = 32; k >= 1; k >>= 1) vv += __shfl_xor(vv, k);
    vv *= (1.f / 64.f);
    float gl = d * (1.f / sqrtf(vv + 1e-5f)) * g_glob[e] + be_glob[e];
    glob_s[e] = gl;
    __syncthreads();

    float vval = in_proj_b[128 + e];
    #pragma unroll
    for (int j = 0; j < 64; ++j) vval = fmaf(glob_s[j], in_proj_w[(128 + e) * 64 + j], vval);
    vs[e] = vval;
    __syncthreads();

    float ao = out_b[e];
    #pragma unroll
    for (int j = 0; j < 64; ++j) ao = fmaf(vs[j], out_w[e * 64 + j], ao);
    aos[e] = ao;
    __syncthreads();

    if (e < 32) {
        float hm = mlp_b1[e];
        #pragma unroll
        for (int j = 0; j < 64; ++j) hm = fmaf(aos[j], mlp_w1[j * 32 + e], hm);
        hms[e] = fmaxf(hm, 0.f);
    }
    __syncthreads();

    if (e < 10) {
        float o = mlp_b2[e];
        #pragma unroll
        for (int i = 0; i < 32; ++i) o = fmaf(hms[i], mlp_w2[i * 10 + e], o);
        out[b * 10 + e] = o;
    }
}

extern "C" void kernel_launch(void* const* d_in, const int* in_sizes, int n_in,
                              void* d_out, int out_size, void* d_ws, size_t ws_size,
                              hipStream_t stream) {
    const float* x        = (const float*)d_in[0];
    const float* conv1_w  = (const float*)d_in[6];
    const float* conv1_b  = (const float*)d_in[7];
    const float* conv2_w  = (const float*)d_in[8];
    const float* conv2_b  = (const float*)d_in[9];
    const float* w_glob   = (const float*)d_in[10];
    const float* b_glob   = (const float*)d_in[11];
    const float* g_glob   = (const float*)d_in[12];
    const float* be_glob  = (const float*)d_in[13];
    const float* in_proj_w = (const float*)d_in[14];
    const float* in_proj_b = (const float*)d_in[15];
    const float* out_w    = (const float*)d_in[16];
    const float* out_b    = (const float*)d_in[17];
    const float* mlp_w1   = (const float*)d_in[18];
    const float* mlp_b1   = (const float*)d_in[19];
    const float* mlp_w2   = (const float*)d_in[20];
    const float* mlp_b2   = (const float*)d_in[21];

    _Float16* fragg = (_Float16*)d_ws;                  // 15*64*8*2 = 15360 B
    float* gacc = (float*)((char*)d_ws + 15360);        // 64*32*4 = 8192 B

    hipMemsetAsync((char*)d_ws + 15360, 0, 8192, stream);   // zero gacc (graph node)

    prep_frags<<<15, 64, 0, stream>>>(conv2_w, fragg);

    dim3 grid(NT, 64);
    conv_fused<<<grid, 256, 0, stream>>>(x, conv1_w, conv1_b, conv2_b, fragg, gacc);

    tail_kernel<<<64, 64, 0, stream>>>(gacc, w_glob, b_glob, g_glob, be_glob,
                                       in_proj_w, in_proj_b, out_w, out_b,
                                       mlp_w1, mlp_b1, mlp_w2, mlp_b2,
                                       (float*)d_out);
}

// Round 3
// 122.200 us; speedup vs baseline: 2.4857x; 1.5556x over previous
//
#include <hip/hip_runtime.h>
#include <math.h>

// Round 11: round-0 structure, epilogue fixed. Round-2 lesson: 262K contended
// device-scope atomicAdds onto 8 KB cost ~50 us (WRITE_SIZE 6.1 MB of coherence
// traffic). Replace with block-local LDS reduce + ONE coalesced 32-float store
// per block -> part2[64][16][32] (128 KB, no contention, no memset needed).
// Tail sums 16 partials per oc (was 128 in round 0).
//
// conv2: single-product fp16 MFMA 32x32x16 (validated: absmax 1.2e-4 << 7.5e-4).

typedef __attribute__((ext_vector_type(4))) _Float16 f16x4;
typedef __attribute__((ext_vector_type(8)))  _Float16 f16x8;
typedef __attribute__((ext_vector_type(16))) float    f32x16;

#define WT 64
#define NT 16
#define H1_OFF   0          // 10 rows * 68 cols * 16 ic * 2B = 21760
#define XS_OFF   21760      // 8*144*4 = 4608
#define RED_OFF  26368      // 4 waves * 4 groups * 16 r * 4B = 1024
#define LDS_BYTES 27392

template <int CTRL>
__device__ __forceinline__ float dppf(float v) {
    return __uint_as_float(__builtin_amdgcn_update_dpp(
        0u, __float_as_uint(v), CTRL, 0xF, 0xF, true));
}
#define DPP_XOR1 0xB1       // quad_perm [1,0,3,2]
#define DPP_XOR2 0x4E       // quad_perm [2,3,0,1]
#define DPP_ROR4 0x124      // row_ror:4
#define DPP_ROR8 0x128      // row_ror:8

// Build conv2-weight fp16 MFMA A-fragments once: fragg[15][64][8] (coalesced consumer loads)
__global__ void prep_frags(const float* __restrict__ w2, _Float16* __restrict__ fragg) {
    const int t    = blockIdx.x;       // 0..14 (tap)
    const int lane = threadIdx.x;      // 0..63
    const int kh   = t / 5, kw = t - kh * 5;
    const int oc   = lane & 31;
    const int ic0  = (lane >> 5) * 8;
    f16x8 hv;
    #pragma unroll
    for (int j = 0; j < 8; ++j)
        hv[j] = (_Float16)w2[((oc * 16 + ic0 + j) * 3 + kh) * 5 + kw];
    *(f16x8*)&fragg[(t * 64 + lane) * 8] = hv;
}

__global__ __launch_bounds__(256, 4) void conv_fused(
    const float* __restrict__ x,
    const float* __restrict__ w1, const float* __restrict__ b1,
    const float* __restrict__ b2,
    const _Float16* __restrict__ fragg,
    float* __restrict__ part2)   // [64 b][16 wt][32 oc] block partials (plain stores)
{
    const int wt  = blockIdx.x;      // 0..15
    const int b   = blockIdx.y;      // 0..63
    const int tid = threadIdx.x;     // 0..255
    const int w0  = wt * WT;

    __shared__ __align__(16) unsigned int ldsu[LDS_BYTES / 4];
    _Float16* h1  = (_Float16*)((char*)ldsu + H1_OFF);  // [(rr*68+c)*16+ic], rr=0..9 (0,9 zero)
    float*    xs  = (float*)((char*)ldsu + XS_OFF);     // [8][144]
    float*    red = (float*)((char*)ldsu + RED_OFF);    // [4 wave][4 grp][16 r]

    // ---- per-thread conv1 weights: ic quad q = tid&3 (thread-constant) ----
    const int q = tid & 3;
    float wreg[60];
    float bias1[4];
    #pragma unroll
    for (int j = 0; j < 4; ++j) {
        #pragma unroll
        for (int k = 0; k < 15; ++k) wreg[j * 15 + k] = w1[(q * 4 + j) * 15 + k];
        bias1[j] = b1[q * 4 + j];
    }

    // ---- phase 0: stage x tile (cols t0..t0+139), zero pad rows rr=0,9 ----
    const int t0 = 2 * w0 - 6;
    for (int i = tid; i < 8 * 144; i += 256) {
        int r = i / 144, tl = i - r * 144;
        int t = t0 + tl;
        float v = 0.f;
        if (tl < 140 && t >= 0 && t < 2048) v = x[(b * 8 + r) * 2048 + t];
        xs[i] = v;
    }
    {
        unsigned int* hh = (unsigned int*)h1;
        for (int i = tid; i < 544; i += 256) {       // each padded row = 544 dwords
            hh[i] = 0u; hh[4896 + i] = 0u;
        }
    }
    __syncthreads();

    // ---- phase 1: conv1 + bias + relu + maxpool -> h1 (fp16) ----
    #pragma unroll
    for (int pass = 0; pass < 3; ++pass) {
        if (pass == 2 && tid >= 32) break;
        const int idx = (tid >> 2) + pass * 64;      // 0..135
        const int r   = idx / 17;
        const int c4  = idx - r * 17;
        const int cb  = c4 * 8;
        float xv[3][12];
        #pragma unroll
        for (int pq = 0; pq < 3; ++pq) {
            int rr = r + pq - 1;
            if (rr >= 0 && rr < 8) {
                const float4* p = (const float4*)&xs[rr * 144 + cb];
                float4 a0 = p[0], a1 = p[1], a2 = p[2];
                xv[pq][0]=a0.x; xv[pq][1]=a0.y; xv[pq][2]=a0.z; xv[pq][3]=a0.w;
                xv[pq][4]=a1.x; xv[pq][5]=a1.y; xv[pq][6]=a1.z; xv[pq][7]=a1.w;
                xv[pq][8]=a2.x; xv[pq][9]=a2.y; xv[pq][10]=a2.z; xv[pq][11]=a2.w;
            } else {
                #pragma unroll
                for (int z = 0; z < 12; ++z) xv[pq][z] = 0.f;
            }
        }
        #pragma unroll
        for (int cc = 0; cc < 4; ++cc) {
            const int wc = w0 - 2 + 4 * c4 + cc;
            f16x4 hv;
            #pragma unroll
            for (int j = 0; j < 4; ++j) {
                float c0 = bias1[j], c1 = bias1[j];
                #pragma unroll
                for (int kh = 0; kh < 3; ++kh)
                    #pragma unroll
                    for (int kw = 0; kw < 5; ++kw) {
                        float wgt = wreg[j * 15 + kh * 5 + kw];
                        c0 = fmaf(xv[kh][2 * cc + kw],     wgt, c0);
                        c1 = fmaf(xv[kh][2 * cc + kw + 1], wgt, c1);
                    }
                float v = fmaxf(fmaxf(c0, c1), 0.f);
                if (wc < 0 || wc >= 1024) v = 0.f;
                hv[j] = (_Float16)v;
            }
            *(f16x4*)&h1[((r + 1) * 68 + 4 * c4 + cc) * 16 + q * 4] = hv;  // 8B store
        }
    }
    __syncthreads();

    // ---- phase 2: conv2 via fp16 MFMA. wave handles h rows {2w,2w+1} x wn0 {0,32} ----
    const int lane  = tid & 63;
    const int wave  = tid >> 6;
    const int laneN = lane & 31;
    const int icoff = (lane >> 5) * 8;
    const int half  = lane >> 5;

    f32x16 acc[4];
    #pragma unroll
    for (int nt = 0; nt < 4; ++nt)
        #pragma unroll
        for (int r = 0; r < 16; ++r) acc[nt][r] = 0.f;

    const f16x8* Ag = (const f16x8*)fragg;
    f16x8 a_cur = Ag[lane];                          // tap 0 (L1/L2-resident, coalesced)
    for (int t = 0; t < 15; ++t) {
        f16x8 a_nxt = (t < 14) ? Ag[(t + 1) * 64 + lane] : a_cur;  // 1-deep prefetch
        int kh = t / 5, kw = t - kh * 5;             // wave-uniform
        #pragma unroll
        for (int nt = 0; nt < 4; ++nt) {
            int hrow = 2 * wave + (nt >> 1);
            int wn0  = (nt & 1) * 32;
            int idx  = ((hrow + kh) * 68 + wn0 + laneN + kw) * 16 + icoff;
            f16x8 bv = *(const f16x8*)&h1[idx];
            acc[nt] = __builtin_amdgcn_mfma_f32_32x32x16_f16(a_cur, bv, acc[nt], 0, 0, 0);
        }
        a_cur = a_nxt;
    }

    // ---- epilogue (VALU/DPP): +bias, relu(maxpool) via DPP xor1, 16-lane DPP sum ----
    float b2v[16], sums[16];
    #pragma unroll
    for (int r = 0; r < 16; ++r) {
        b2v[r]  = b2[(r & 3) + 8 * (r >> 2) + 4 * half];
        sums[r] = 0.f;
    }
    #pragma unroll
    for (int nt = 0; nt < 4; ++nt)
        #pragma unroll
        for (int r = 0; r < 16; ++r) {
            float d = acc[nt][r] + b2v[r];
            float o = fmaxf(fmaxf(d, dppf<DPP_XOR1>(d)), 0.f);  // pool pair + relu
            sums[r] += o;                                        // counts each pair twice
        }
    #pragma unroll
    for (int r = 0; r < 16; ++r) {
        float s = sums[r];
        s += dppf<DPP_XOR1>(s);
        s += dppf<DPP_XOR2>(s);
        s += dppf<DPP_ROR4>(s);
        s += dppf<DPP_ROR8>(s);      // full sum within each 16-lane group
        sums[r] = s;
    }

    // ---- block-local reduce in LDS (replaces contended global atomics) ----
    if ((lane & 15) == 0) {          // lanes 0,16,32,48: grp = lane>>4
        const int g = lane >> 4;
        #pragma unroll
        for (int r = 0; r < 16; ++r)
            red[(wave * 4 + g) * 16 + r] = sums[r];
    }
    __syncthreads();
    if (tid < 32) {
        const int oc = tid;
        const int hf = (oc >> 2) & 1;                    // half
        const int r  = (oc & 3) | (((oc >> 3) & 3) << 2);
        float tot = 0.f;
        #pragma unroll
        for (int w = 0; w < 4; ++w)
            tot += red[(w * 4 + 2 * hf) * 16 + r] + red[(w * 4 + 2 * hf + 1) * 16 + r];
        part2[(b * 16 + wt) * 32 + oc] = 0.5f * tot;     // coalesced 128 B/block
    }
}

__global__ void tail_kernel(
    const float* __restrict__ part2,
    const float* __restrict__ w_glob, const float* __restrict__ b_glob,
    const float* __restrict__ g_glob, const float* __restrict__ be_glob,
    const float* __restrict__ in_proj_w, const float* __restrict__ in_proj_b,
    const float* __restrict__ out_w, const float* __restrict__ out_b,
    const float* __restrict__ mlp_w1, const float* __restrict__ mlp_b1,
    const float* __restrict__ mlp_w2, const float* __restrict__ mlp_b2,
    float* __restrict__ out)
{
    const int b = blockIdx.x;        // 0..63
    const int e = threadIdx.x;       // 0..63 (one wave)
    __shared__ float gs[32], glob_s[64], vs[64], aos[64], hms[32];

    if (e < 32) {
        float sm = 0.f;
        #pragma unroll
        for (int t = 0; t < 16; ++t) sm += part2[(b * 16 + t) * 32 + e];
        gs[e] = sm * (1.f / 4096.f);  // mean over 8*512
    }
    __syncthreads();

    float acc = b_glob[e];
    #pragma unroll
    for (int i = 0; i < 32; ++i) acc = fmaf(gs[i], w_glob[i * 64 + e], acc);
    acc = fmaxf(acc, 0.f);

    float m = acc;
    #pragma unroll
    for (int k = 32; k >= 1; k >>= 1) m += __shfl_xor(m, k);
    m *= (1.f / 64.f);
    float d = acc - m;
    float vv = d * d;
    #pragma unroll
    for (int k = 32; k >= 1; k >>= 1) vv += __shfl_xor(vv, k);
    vv *= (1.f / 64.f);
    float gl = d * (1.f / sqrtf(vv + 1e-5f)) * g_glob[e] + be_glob[e];
    glob_s[e] = gl;
    __syncthreads();

    float vval = in_proj_b[128 + e];
    #pragma unroll
    for (int j = 0; j < 64; ++j) vval = fmaf(glob_s[j], in_proj_w[(128 + e) * 64 + j], vval);
    vs[e] = vval;
    __syncthreads();

    float ao = out_b[e];
    #pragma unroll
    for (int j = 0; j < 64; ++j) ao = fmaf(vs[j], out_w[e * 64 + j], ao);
    aos[e] = ao;
    __syncthreads();

    if (e < 32) {
        float hm = mlp_b1[e];
        #pragma unroll
        for (int j = 0; j < 64; ++j) hm = fmaf(aos[j], mlp_w1[j * 32 + e], hm);
        hms[e] = fmaxf(hm, 0.f);
    }
    __syncthreads();

    if (e < 10) {
        float o = mlp_b2[e];
        #pragma unroll
        for (int i = 0; i < 32; ++i) o = fmaf(hms[i], mlp_w2[i * 10 + e], o);
        out[b * 10 + e] = o;
    }
}

extern "C" void kernel_launch(void* const* d_in, const int* in_sizes, int n_in,
                              void* d_out, int out_size, void* d_ws, size_t ws_size,
                              hipStream_t stream) {
    const float* x        = (const float*)d_in[0];
    const float* conv1_w  = (const float*)d_in[6];
    const float* conv1_b  = (const float*)d_in[7];
    const float* conv2_w  = (const float*)d_in[8];
    const float* conv2_b  = (const float*)d_in[9];
    const float* w_glob   = (const float*)d_in[10];
    const float* b_glob   = (const float*)d_in[11];
    const float* g_glob   = (const float*)d_in[12];
    const float* be_glob  = (const float*)d_in[13];
    const float* in_proj_w = (const float*)d_in[14];
    const float* in_proj_b = (const float*)d_in[15];
    const float* out_w    = (const float*)d_in[16];
    const float* out_b    = (const float*)d_in[17];
    const float* mlp_w1   = (const float*)d_in[18];
    const float* mlp_b1   = (const float*)d_in[19];
    const float* mlp_w2   = (const float*)d_in[20];
    const float* mlp_b2   = (const float*)d_in[21];

    _Float16* fragg = (_Float16*)d_ws;                  // 15*64*8*2 = 15360 B
    float* part2 = (float*)((char*)d_ws + 15360);       // 64*16*32*4 = 131072 B

    prep_frags<<<15, 64, 0, stream>>>(conv2_w, fragg);

    dim3 grid(NT, 64);
    conv_fused<<<grid, 256, 0, stream>>>(x, conv1_w, conv1_b, conv2_b, fragg, part2);

    tail_kernel<<<64, 64, 0, stream>>>(part2, w_glob, b_glob, g_glob, be_glob,
                                       in_proj_w, in_proj_b, out_w, out_b,
                                       mlp_w1, mlp_b1, mlp_w2, mlp_b2,
                                       (float*)d_out);
}